// Round 2
// baseline (2216.909 us; speedup 1.0000x reference)
//
#include <hip/hip_runtime.h>
#include <stdint.h>
#include <stddef.h>

#define NUM_EXPERT 16
#define IN_FEAT 2048
#define OUT_FEAT 8192
#define TOTAL_TOKENS 8192

// ---- pipelined kernel geometry ----
#define BM 256
#define BN 256
#define BK 32
#define NKT (IN_FEAT / BK)         // 64 K-tiles
#define NT_TILES (OUT_FEAT / BN)   // 32
#define MAX_SLOTS 48               // sum ceil(c_e/256) <= 47; grid 32*48=1536 (%8==0)

typedef __attribute__((ext_vector_type(8))) short short8;     // 8 bf16 = 4 VGPRs
typedef __attribute__((ext_vector_type(4))) float floatx4;
typedef __attribute__((ext_vector_type(4))) uint32_t uintx4;

union UCast { uintx4 u; short8 s; };

// pack two fp32 -> two bf16 (round-half-up; v_perm combines high halves)
__device__ __forceinline__ uint32_t pk_bf16(float a, float b) {
    uint32_t ua = __float_as_uint(a) + 0x8000u;
    uint32_t ub = __float_as_uint(b) + 0x8000u;
    return __builtin_amdgcn_perm(ub, ua, 0x07060302u);
}

// async 16B global->LDS (wave-uniform LDS base + lane*16)
__device__ __forceinline__ void cp16_to_lds(const void* g, void* l) {
    __builtin_amdgcn_global_load_lds(
        (const __attribute__((address_space(1))) uint32_t*)g,
        (__attribute__((address_space(3))) uint32_t*)l, 16, 0, 0);
}

// pre-pass: inp fp32 [8192 x 2048] -> bf16 in ws
__global__ __launch_bounds__(256) void cvt_a_kernel(const float* __restrict__ inp,
                                                    uint16_t* __restrict__ dst) {
    size_t base = ((size_t)blockIdx.x * 256 + threadIdx.x) * 8;
    floatx4 f0 = ((const floatx4*)(inp + base))[0];
    floatx4 f1 = ((const floatx4*)(inp + base))[1];
    uintx4 d;
    d.x = pk_bf16(f0.x, f0.y);
    d.y = pk_bf16(f0.z, f0.w);
    d.z = pk_bf16(f1.x, f1.y);
    d.w = pk_bf16(f1.z, f1.w);
    *(uintx4*)(dst + base) = d;
}

// ---------------------------------------------------------------------------
// Pipelined grouped GEMM (T3+T4): triple-buffered LDS, stage 2 K-tiles ahead,
// counted s_waitcnt vmcnt(6) + raw s_barrier (never drain to 0 in main loop).
// A: bf16 ws via global_load_lds, k-outer chunks c = p*256 + r  (p = k/8)
// B: fp32 W  via global_load_lds, k-outer chunks c = p4*256 + n (p4 = k/4),
//    converted fp32->bf16 at fragment-read time (4 pk per frag).
// 512 threads = 8 waves (2m x 4n), wave tile 128x64, acc[8][4].
// ---------------------------------------------------------------------------
__global__ __launch_bounds__(512, 2)
void moe_gemm_pipe(const float* __restrict__ W,
                   const uint16_t* __restrict__ Abf,
                   const int* __restrict__ cnt_raw,
                   float* __restrict__ out) {
    // XCD-swizzled 1D grid (slot fastest): blocks sharing a W panel are
    // concurrent on one XCD -> L2-hot; each (e,nt) panel lives on one XCD.
    const int nwg = (int)gridDim.x;        // 1536, %8==0
    const int orig = (int)blockIdx.x;
    const int wgid = (orig & 7) * (nwg >> 3) + (orig >> 3);
    const int slot = wgid % MAX_SLOTS;
    const int nt = wgid / MAX_SLOTS;

    // counts dtype autodetect (int32 expected; int64 low words if JAX x64)
    int sum32 = 0;
#pragma unroll
    for (int i = 0; i < NUM_EXPERT; ++i) sum32 += cnt_raw[i];
    const int idxmul = (sum32 == TOTAL_TOKENS) ? 1 : 2;

    // slot -> (expert, local tile)
    int e = -1, lt = 0, cnt = 0, row0 = 0;
    {
        int off = 0, tacc = 0;
#pragma unroll
        for (int i = 0; i < NUM_EXPERT; ++i) {
            int c = cnt_raw[i * idxmul];
            int t = (c + BM - 1) >> 8;
            if (e < 0 && slot < tacc + t) {
                e = i; lt = slot - tacc; cnt = c; row0 = off + lt * BM;
            }
            tacc += t; off += c;
        }
    }
    if (e < 0) return;

    const int tid = (int)threadIdx.x;
    const int lane = tid & 63;
    const int w = tid >> 6;    // wave 0..7
    const int wm = w & 1;      // wave m-row (128 rows)
    const int wn = w >> 1;     // wave n-col (64 cols)
    const int l15 = lane & 15;
    const int l4 = lane >> 4;

    // flat LDS: A 3 tiles x 8192 uint16 (16 KB), B 3 tiles x 8192 float (32 KB)
    __shared__ uint16_t Ash[3 * 8192];   // 48 KiB
    __shared__ float    Bsh[3 * 8192];   // 96 KiB   (total 144 KiB)

    // ---- staging source pointers (kt=0 base; advance by kt*BK elems) ----
    // A inst i in {0,1}: chunk c = i*512 + tid -> r = c&255, p = (c>>8)
    const int ar = tid & 255;
    const int ap = tid >> 8;                       // 0 or 1
    const int gr = min(row0 + ar, TOTAL_TOKENS - 1);
    const uint16_t* aS = Abf + (size_t)gr * IN_FEAT + ap * 8;   // inst1 = +16
    // B inst i in {0..3}: chunk c = i*512 + tid -> n = c&255, p4 = (c>>8)
    const float* bS = W + ((size_t)e * OUT_FEAT + (size_t)nt * BN + ar) * IN_FEAT + ap * 4;
    // wave-uniform LDS dest chunk bases (lane*16B implicit)
    const int aDc = w * 64;            // + i*512 chunks
    const int bDc = w * 64;

    // ---- fragment read indices (chunk units, constant over loop) ----
    int aidx[8];
#pragma unroll
    for (int mi = 0; mi < 8; ++mi) aidx[mi] = l4 * 256 + wm * 128 + mi * 16 + l15;
    int bidx[4];
#pragma unroll
    for (int nj = 0; nj < 4; ++nj) bidx[nj] = l4 * 512 + wn * 64 + nj * 16 + l15;

    floatx4 acc[8][4] = {};

    // ---- prologue: stage K-tiles 0 and 1 (12 loads outstanding) ----
#pragma unroll
    for (int t0 = 0; t0 < 2; ++t0) {
        const uint16_t* ap_ = aS + t0 * BK;
        uint16_t* ad = &Ash[0] + t0 * 8192 + aDc * 8;
        cp16_to_lds(ap_,      ad);
        cp16_to_lds(ap_ + 16, ad + 512 * 8);
        const float* bp_ = bS + t0 * BK;
        float* bd = &Bsh[0] + t0 * 8192 + bDc * 4;
        cp16_to_lds(bp_,      bd);
        cp16_to_lds(bp_ + 8,  bd + 512 * 4);
        cp16_to_lds(bp_ + 16, bd + 1024 * 4);
        cp16_to_lds(bp_ + 24, bd + 1536 * 4);
    }

    int cb = 0;  // compute buffer (t % 3)
    for (int t = 0; t < NKT; ++t) {
        const int sb = (cb + 2 >= 3) ? cb - 1 : cb + 2;   // stage buffer (t+2)%3

        // tile t's 6 loads landed (allow tile t+1's 6 in flight); all waves
        // done reading tile t-1 (whose buffer == sb) before we overwrite it.
        asm volatile("s_waitcnt vmcnt(6)" ::: "memory");
        __builtin_amdgcn_s_barrier();
        asm volatile("" ::: "memory");

        // ---- stage tile t+2 into sb (clamped source keeps counts uniform) ----
        {
            const int kts = (t + 2 < NKT) ? t + 2 : NKT - 1;
            const uint16_t* ap_ = aS + kts * BK;
            uint16_t* ad = &Ash[0] + sb * 8192 + aDc * 8;
            cp16_to_lds(ap_,      ad);
            cp16_to_lds(ap_ + 16, ad + 512 * 8);
            const float* bp_ = bS + kts * BK;
            float* bd = &Bsh[0] + sb * 8192 + bDc * 4;
            cp16_to_lds(bp_,      bd);
            cp16_to_lds(bp_ + 8,  bd + 512 * 4);
            cp16_to_lds(bp_ + 16, bd + 1024 * 4);
            cp16_to_lds(bp_ + 24, bd + 1536 * 4);
        }

        // ---- compute tile t from cb ----
        const short8* Ach = (const short8*)(&Ash[0] + cb * 8192);
        const floatx4* Bf = (const floatx4*)(&Bsh[0] + cb * 8192);

        short8 bv[4];
#pragma unroll
        for (int nj = 0; nj < 4; ++nj) {
            floatx4 lo = Bf[bidx[nj]];
            floatx4 hi = Bf[bidx[nj] + 256];
            UCast u;
            u.u.x = pk_bf16(lo.x, lo.y); u.u.y = pk_bf16(lo.z, lo.w);
            u.u.z = pk_bf16(hi.x, hi.y); u.u.w = pk_bf16(hi.z, hi.w);
            bv[nj] = u.s;
        }
#pragma unroll
        for (int g = 0; g < 2; ++g) {
            short8 av[4];
#pragma unroll
            for (int k = 0; k < 4; ++k) av[k] = Ach[aidx[g * 4 + k]];
            __builtin_amdgcn_s_setprio(1);
#pragma unroll
            for (int k = 0; k < 4; ++k)
#pragma unroll
                for (int nj = 0; nj < 4; ++nj)
                    acc[g * 4 + k][nj] = __builtin_amdgcn_mfma_f32_16x16x32_bf16(
                        av[k], bv[nj], acc[g * 4 + k][nj], 0, 0, 0);
            __builtin_amdgcn_s_setprio(0);
        }

        cb = (cb + 1 >= 3) ? 0 : cb + 1;
    }

    // ---- epilogue: C/D layout col = lane&15, row = (lane>>4)*4 + reg ----
    const int cnt_loc = cnt - lt * BM;  // valid rows in this tile (1..256)
    const size_t col = (size_t)nt * BN + wn * 64 + l15;
#pragma unroll
    for (int mi = 0; mi < 8; ++mi) {
        int rb = wm * 128 + mi * 16 + l4 * 4;
#pragma unroll
        for (int reg = 0; reg < 4; ++reg) {
            int r = rb + reg;
            if (r < cnt_loc) {
                float* rp = out + (size_t)(row0 + r) * OUT_FEAT + col;
                rp[0]  = acc[mi][0][reg];
                rp[16] = acc[mi][1][reg];
                rp[32] = acc[mi][2][reg];
                rp[48] = acc[mi][3][reg];
            }
        }
    }
}

// ---------------------------------------------------------------------------
// Fallback (no workspace): round-1 reg-staged kernel, BM=256 BN=128 BK=32,
// double-buffered, one __syncthreads per K-step. Known-correct.
// ---------------------------------------------------------------------------
__global__ __launch_bounds__(512, 4)
void moe_gemm_fb(const float* __restrict__ W,
                 const float* __restrict__ inp,
                 const int* __restrict__ cnt_raw,
                 float* __restrict__ out) {
    const int nwg = (int)gridDim.x;      // 3072
    const int orig = (int)blockIdx.x;
    const int wgid = (orig & 7) * (nwg >> 3) + (orig >> 3);
    const int slot = wgid % 48;
    const int nt = wgid / 48;            // 0..63 (BN=128)

    int sum32 = 0;
#pragma unroll
    for (int i = 0; i < NUM_EXPERT; ++i) sum32 += cnt_raw[i];
    const int idxmul = (sum32 == TOTAL_TOKENS) ? 1 : 2;

    int e = -1, lt = 0, cnt = 0, row0 = 0;
    {
        int off = 0, tacc = 0;
#pragma unroll
        for (int i = 0; i < NUM_EXPERT; ++i) {
            int c = cnt_raw[i * idxmul];
            int t = (c + 255) >> 8;
            if (e < 0 && slot < tacc + t) {
                e = i; lt = slot - tacc; cnt = c; row0 = off + lt * 256;
            }
            tacc += t; off += c;
        }
    }
    if (e < 0) return;

    const int tid = (int)threadIdx.x;
    const int lane = tid & 63;
    const int w = tid >> 6;
    const int wm = w & 3;
    const int wn = w >> 2;
    const int l15 = lane & 15;
    const int l4 = lane >> 4;

    __shared__ uint16_t Abuf[2][256 * 32];
    __shared__ uint16_t Bbuf[2][128 * 32];

    const int bn_ = tid & 127;
    const int bp_ = tid >> 7;
    const float* bg = W + ((size_t)e * OUT_FEAT + (size_t)nt * 128 + bn_) * IN_FEAT + bp_ * 8;
    const int boff = (bp_ * 128 + bn_) * 8;

    int r = tid & 255;
    int pb = (tid >> 8) * 2;
    int grr = min(row0 + r, TOTAL_TOKENS - 1);
    const float* ia = inp + (size_t)grr * IN_FEAT + pb * 8;
    const int foff0 = (pb * 256 + r) * 8;
    const int foff1 = ((pb + 1) * 256 + r) * 8;

    int aidx[4], bidx[4];
#pragma unroll
    for (int i = 0; i < 4; ++i) aidx[i] = l4 * 256 + wm * 64 + i * 16 + l15;
#pragma unroll
    for (int j = 0; j < 4; ++j) bidx[j] = l4 * 128 + wn * 64 + j * 16 + l15;

    floatx4 acc[4][4] = {};

    {
        floatx4 b0 = ((const floatx4*)bg)[0];
        floatx4 b1 = ((const floatx4*)bg)[1];
        floatx4 a0 = ((const floatx4*)ia)[0];
        floatx4 a1 = ((const floatx4*)ia)[1];
        floatx4 a2 = ((const floatx4*)ia)[2];
        floatx4 a3 = ((const floatx4*)ia)[3];
        uintx4 da0, da1;
        da0.x = pk_bf16(a0.x, a0.y); da0.y = pk_bf16(a0.z, a0.w);
        da0.z = pk_bf16(a1.x, a1.y); da0.w = pk_bf16(a1.z, a1.w);
        da1.x = pk_bf16(a2.x, a2.y); da1.y = pk_bf16(a2.z, a2.w);
        da1.z = pk_bf16(a3.x, a3.y); da1.w = pk_bf16(a3.z, a3.w);
        *(uintx4*)(Abuf[0] + foff0) = da0;
        *(uintx4*)(Abuf[0] + foff1) = da1;
        ia += 32;
        uintx4 db;
        db.x = pk_bf16(b0.x, b0.y); db.y = pk_bf16(b0.z, b0.w);
        db.z = pk_bf16(b1.x, b1.y); db.w = pk_bf16(b1.z, b1.w);
        *(uintx4*)(Bbuf[0] + boff) = db;
        bg += 32;
        __syncthreads();
    }

    for (int ks = 0; ks < 63; ++ks) {
        const int cur = ks & 1, nxt = cur ^ 1;
        floatx4 b0 = ((const floatx4*)bg)[0];
        floatx4 b1 = ((const floatx4*)bg)[1];
        floatx4 a0 = ((const floatx4*)ia)[0];
        floatx4 a1 = ((const floatx4*)ia)[1];
        floatx4 a2 = ((const floatx4*)ia)[2];
        floatx4 a3 = ((const floatx4*)ia)[3];
        ia += 32; bg += 32;

        const short8* Ach = (const short8*)Abuf[cur];
        const short8* Bch = (const short8*)Bbuf[cur];
        short8 av[4], bv[4];
#pragma unroll
        for (int j = 0; j < 4; ++j) bv[j] = Bch[bidx[j]];
#pragma unroll
        for (int i = 0; i < 4; ++i) av[i] = Ach[aidx[i]];
#pragma unroll
        for (int i = 0; i < 4; ++i)
#pragma unroll
            for (int j = 0; j < 4; ++j)
                acc[i][j] = __builtin_amdgcn_mfma_f32_16x16x32_bf16(av[i], bv[j], acc[i][j], 0, 0, 0);

        uintx4 da0, da1;
        da0.x = pk_bf16(a0.x, a0.y); da0.y = pk_bf16(a0.z, a0.w);
        da0.z = pk_bf16(a1.x, a1.y); da0.w = pk_bf16(a1.z, a1.w);
        da1.x = pk_bf16(a2.x, a2.y); da1.y = pk_bf16(a2.z, a2.w);
        da1.z = pk_bf16(a3.x, a3.y); da1.w = pk_bf16(a3.z, a3.w);
        *(uintx4*)(Abuf[nxt] + foff0) = da0;
        *(uintx4*)(Abuf[nxt] + foff1) = da1;
        uintx4 db;
        db.x = pk_bf16(b0.x, b0.y); db.y = pk_bf16(b0.z, b0.w);
        db.z = pk_bf16(b1.x, b1.y); db.w = pk_bf16(b1.z, b1.w);
        *(uintx4*)(Bbuf[nxt] + boff) = db;
        __syncthreads();
    }

    {
        const short8* Ach = (const short8*)Abuf[1];
        const short8* Bch = (const short8*)Bbuf[1];
        short8 av[4], bv[4];
#pragma unroll
        for (int j = 0; j < 4; ++j) bv[j] = Bch[bidx[j]];
#pragma unroll
        for (int i = 0; i < 4; ++i) av[i] = Ach[aidx[i]];
#pragma unroll
        for (int i = 0; i < 4; ++i)
#pragma unroll
            for (int j = 0; j < 4; ++j)
                acc[i][j] = __builtin_amdgcn_mfma_f32_16x16x32_bf16(av[i], bv[j], acc[i][j], 0, 0, 0);
    }

    const int cnt_loc = cnt - lt * 256;
    const size_t col = (size_t)nt * 128 + wn * 64 + l15;
#pragma unroll
    for (int i = 0; i < 4; ++i) {
        int rb = wm * 64 + i * 16 + l4 * 4;
#pragma unroll
        for (int reg = 0; reg < 4; ++reg) {
            int rr = rb + reg;
            if (rr < cnt_loc) {
                float* rp = out + (size_t)(row0 + rr) * OUT_FEAT + col;
                rp[0]  = acc[i][0][reg];
                rp[16] = acc[i][1][reg];
                rp[32] = acc[i][2][reg];
                rp[48] = acc[i][3][reg];
            }
        }
    }
}

extern "C" void kernel_launch(void* const* d_in, const int* in_sizes, int n_in,
                              void* d_out, int out_size, void* d_ws, size_t ws_size,
                              hipStream_t stream) {
    const float* inp = (const float*)d_in[0];
    const float* W = (const float*)d_in[1];
    const int* counts = (const int*)d_in[2];
    float* out = (float*)d_out;

    const size_t abytes = (size_t)TOTAL_TOKENS * IN_FEAT * sizeof(uint16_t);  // 32 MiB

    if (ws_size >= abytes) {
        uint16_t* Abf = (uint16_t*)d_ws;
        int nblk = (int)(((size_t)TOTAL_TOKENS * IN_FEAT) / (256 * 8));  // 8192
        cvt_a_kernel<<<nblk, 256, 0, stream>>>(inp, Abf);
        dim3 grid(NT_TILES * MAX_SLOTS);  // 1536
        moe_gemm_pipe<<<grid, 512, 0, stream>>>(W, Abf, counts, out);
    } else {
        dim3 grid(64 * 48);  // 3072
        moe_gemm_fb<<<grid, 512, 0, stream>>>(W, inp, counts, out);
    }
}